// Round 11
// baseline (3453.133 us; speedup 1.0000x reference)
//
#include <hip/hip_runtime.h>
#include <hip/hip_bf16.h>

#define NCLS 3
#define NPTS 64
#define NEDGE 2016   // 64*63/2
#define MIN_SAMP 200

__device__ int          g_counts[NCLS];
__device__ int          g_sel[NCLS][NPTS];
__device__ float        g_Dm[NCLS][NPTS * NPTS];
__device__ float        g_tp[NCLS];
__device__ int          g_ovf[NCLS];
__device__ unsigned int g_rows[NCLS][NEDGE][64];   // fallback-only state

__global__ void init_k() {
    if (threadIdx.x < NCLS) { g_counts[threadIdx.x] = 0; g_ovf[threadIdx.x] = 0; }
}

__global__ __launch_bounds__(256) void count_k(const int* __restrict__ labels, int N) {
    __shared__ int c3[NCLS];
    if (threadIdx.x < NCLS) c3[threadIdx.x] = 0;
    __syncthreads();
    for (int i = blockIdx.x * blockDim.x + threadIdx.x; i < N; i += gridDim.x * blockDim.x) {
        int c = labels[i];
        if ((unsigned)c < NCLS) atomicAdd(&c3[c], 1);
    }
    __syncthreads();
    if (threadIdx.x < NCLS) atomicAdd(&g_counts[threadIdx.x], c3[threadIdx.x]);
}

__global__ __launch_bounds__(64) void select_k(const int* __restrict__ labels, int N) {
    const int lane = threadIdx.x;
    int cnt[NCLS] = {0, 0, 0};
    for (int base = 0; base < N; base += 64) {
        if (cnt[0] >= NPTS && cnt[1] >= NPTS && cnt[2] >= NPTS) break;
        int lab = (base + lane < N) ? labels[base + lane] : -1;
        for (int c = 0; c < NCLS; ++c) {
            if (cnt[c] >= NPTS) continue;
            unsigned long long m = __ballot(lab == c);
            if (!m) continue;
            int pos = cnt[c] + __popcll(m & ((1ull << lane) - 1ull));
            if (lab == c && pos < NPTS) g_sel[c][pos] = base + lane;
            cnt[c] = min(NPTS, cnt[c] + (int)__popcll(m));
        }
    }
}

__global__ __launch_bounds__(256) void dist_k(const float* __restrict__ feat) {
    int cls = blockIdx.x;
    if (g_counts[cls] < MIN_SAMP) return;
    int p = blockIdx.y * 256 + threadIdx.x;
    int i = p >> 6, j = p & 63;
    const float4* pi = (const float4*)(feat + (size_t)g_sel[cls][i] * 768);
    const float4* pj = (const float4*)(feat + (size_t)g_sel[cls][j] * 768);
    float sq = 0.f;
    #pragma unroll 4
    for (int d = 0; d < 192; ++d) {
        float4 va = pi[d], vb = pj[d];
        float dx = va.x - vb.x, dy = va.y - vb.y, dz = va.z - vb.z, dw = va.w - vb.w;
        sq = fmaf(dx, dx, sq); sq = fmaf(dy, dy, sq);
        sq = fmaf(dz, dz, sq); sq = fmaf(dw, dw, sq);
    }
    g_Dm[cls][p] = sqrtf(fmaxf(sq, 1e-12f));
}

__device__ __forceinline__ uint4 shfl4(uint4 v, int src) {
    uint4 r;
    r.x = (unsigned)__shfl((int)v.x, src);
    r.y = (unsigned)__shfl((int)v.y, src);
    r.z = (unsigned)__shfl((int)v.z, src);
    r.w = (unsigned)__shfl((int)v.w, src);
    return r;
}
__device__ __forceinline__ void xor4(uint4& a, const uint4 b) {
    a.x ^= b.x; a.y ^= b.y; a.z ^= b.z; a.w ^= b.w;
}
__device__ __forceinline__ unsigned int getw4(const uint4 a, int m) {
    return (m < 32) ? a.x : (m < 64) ? a.y : (m < 96) ? a.z : a.w;
}
__device__ __forceinline__ void set4(uint4& a, int m) {
    const unsigned int b = 1u << (m & 31);
    if (m < 32) a.x |= b; else if (m < 64) a.y |= b; else if (m < 96) a.z |= b; else a.w |= b;
}
__device__ __forceinline__ bool any4(const uint4 a, const uint4 b) {
    return ((a.x & b.x) | (a.y & b.y) | (a.z & b.z) | (a.w & b.w)) != 0u;
}
__device__ __forceinline__ int ffs4set(uint4& f) {   // pop first set bit
    int s = (f.x) ? __builtin_ctz(f.x) : (f.y) ? 32 + __builtin_ctz(f.y)
          : (f.z) ? 64 + __builtin_ctz(f.z) : (f.w) ? 96 + __builtin_ctz(f.w) : -1;
    if (s >= 0) {
        unsigned int b = 1u << (s & 31);
        if (s < 32) f.x &= ~b; else if (s < 64) f.y &= ~b; else if (s < 96) f.z &= ~b; else f.w &= ~b;
    }
    return s;
}
__device__ __forceinline__ int nth_set_bit64(unsigned long long m, int n) {
    int idx = 0;
    unsigned int lo = (unsigned int)m;
    int c = __builtin_popcount(lo);
    if (n >= c) { n -= c; idx = 32; lo = (unsigned int)(m >> 32); }
    c = __builtin_popcount(lo & 0xffffu);
    if (n >= c) { n -= c; idx += 16; lo >>= 16; }
    c = __builtin_popcount(lo & 0xffu);
    if (n >= c) { n -= c; idx += 8; lo >>= 8; }
    c = __builtin_popcount(lo & 0xfu);
    if (n >= c) { n -= c; idx += 4; lo >>= 4; }
    c = __builtin_popcount(lo & 0x3u);
    if (n >= c) { n -= c; idx += 2; lo >>= 2; }
    if (n >= (int)(lo & 1u)) idx += 1;
    return idx;
}
#define SEL4(g, a0, a1, a2, a3) ((g) == 0 ? (a0) : (g) == 1 ? (a1) : (g) == 2 ? (a2) : (a3))

// Serial-chain apply, pivot-indexed (validated R10): 1 LDS load per pending bit.
__device__ __forceinline__ uint4 pend_apply(uint4 v, const uint4 pm, const uint4* pend) {
    unsigned int w;
    w = v.x & pm.x;
    while (w) { int c = __builtin_ctz(w); w &= w - 1; xor4(v, pend[c]); }
    w = v.y & pm.y;
    while (w) { int c = __builtin_ctz(w); w &= w - 1; xor4(v, pend[32 + c]); }
    w = v.z & pm.z;
    while (w) { int c = __builtin_ctz(w); w &= w - 1; xor4(v, pend[64 + c]); }
    w = v.w & pm.w;
    while (w) { int c = __builtin_ctz(w); w &= w - 1; xor4(v, pend[96 + c]); }
    return v;
}

// Wave-synchronous GJ over per-lane candidate vectors (lane order = filtration
// order) + append to the mutually-reduced pending list. evl = per-lane group value.
__device__ __forceinline__ void gj_append(uint4 v, float evl, int lane,
                                          uint4* s_pend, unsigned char* s_plist,
                                          int& plc, uint4& pendmask, double& death) {
    uint4 s4 = make_uint4(0u, 0u, 0u, 0u);
    int accidx = -1, accm = 0, d = 0;
    while (true) {
        unsigned long long nzm = __ballot((v.x | v.y | v.z | v.w) != 0u);
        if (!nzm) break;
        const int l = __builtin_ctzll(nzm);
        const uint4 p = shfl4(v, l);
        const float evp = __shfl(evl, l);
        const int m = p.x ? __builtin_ctz(p.x) : p.y ? 32 + __builtin_ctz(p.y)
                   : p.z ? 64 + __builtin_ctz(p.z) : 96 + __builtin_ctz(p.w);
        if (lane == l) { s4 = v; accidx = d; accm = m; }
        const unsigned int mb2 = 1u << (m & 31);
        if (getw4(v, m) & mb2) xor4(v, p);
        if (accidx >= 0 && accidx < d) {
            if (getw4(s4, m) & mb2) xor4(s4, p);
        }
        death += (double)evp;
        ++d;
    }
    if (!d) return;
    if (accidx >= 0) {
        s_pend[accm] = s4;
        s_plist[plc + accidx] = (unsigned char)accm;
    }
    uint4 npm = make_uint4(0u, 0u, 0u, 0u);
    for (int t = 0; t < d; ++t) {
        const unsigned long long who = __ballot(accidx == t);
        const int l = __builtin_ctzll(who);
        const int m = __shfl(accm, l);
        set4(npm, m);
    }
    for (int x = lane; x < plc; x += 64) {
        const int p = s_plist[x];
        uint4 q = s_pend[p];
        if (any4(q, npm)) s_pend[p] = pend_apply(q, npm, s_pend);
    }
    plc += d;
    pendmask.x |= npm.x; pendmask.y |= npm.y;
    pendmask.z |= npm.z; pendmask.w |= npm.w;
}

// ---------------- fast path: annotation H1 persistence, batched groups ----------------
// Singles (R7-validated body) until the DSU tree completes (63 merges); afterwards
// every edge is positive and up to 4 consecutive groups are processed per wave-pass:
// pre-allocated slots, parallel events, candidates packed group-major into lanes,
// one GJ+append per batch (exact: lane order == filtration order).
__global__ __launch_bounds__(1024) void persist_fast_k() {
    const int cls  = blockIdx.x;
    const int tid  = threadIdx.x;
    const int lane = tid & 63;
    const int wid  = tid >> 6;
    if (g_counts[cls] < MIN_SAMP) return;

    __shared__ union UA {
        float sDm[NPTS * NPTS];          // ranking phase (16 KB)
        uint4 M[NEDGE];                  // edge annotations (32.25 KB)
    } uA;
    __shared__ uint4          Mv[NPTS];                 // vertex potentials (1 KB)
    __shared__ short          rank2d[NPTS * NPTS];      // 8 KB
    __shared__ unsigned short se_ij[NEDGE];             // 4 KB (i | j<<8, by rank)
    __shared__ float          ev[NEDGE];                // 8 KB
    __shared__ unsigned char  e2i[NEDGE], e2j[NEDGE];   // 4 KB (ranking only)
    __shared__ uint4          s_pend[128];              // 2 KB, indexed by pivot slot
    __shared__ unsigned char  s_plist[128];

    for (int p = tid; p < NPTS * NPTS; p += 1024) uA.sDm[p] = g_Dm[cls][p];
    if (tid < NPTS - 1) {
        int i = tid;
        int base = i * (2 * NPTS - 1 - i) / 2;
        for (int j = i + 1; j < NPTS; ++j) {
            e2i[base + j - i - 1] = (unsigned char)i;
            e2j[base + j - i - 1] = (unsigned char)j;
        }
    }
    if (tid < NPTS) rank2d[tid * NPTS + tid] = 0x7fff;   // diagonal guard
    if (tid < NPTS) Mv[tid] = make_uint4(0u, 0u, 0u, 0u);
    __syncthreads();

    // Rank edges by (value, i, j) — matches reference lexsort((jj,ii,vals)).
    for (int e = tid; e < NEDGE; e += 1024) {
        int i_ = e2i[e], j_ = e2j[e];
        float v = uA.sDm[i_ * NPTS + j_];
        int rk = 0;
        for (int f = 0; f < NEDGE; ++f) {
            int fi = e2i[f], fj = e2j[f];
            float w = uA.sDm[fi * NPTS + fj];
            bool less = (w < v) || (w == v && (fi < i_ || (fi == i_ && fj < j_)));
            rk += less ? 1 : 0;
        }
        se_ij[rk] = (unsigned short)(i_ | (j_ << 8));
        ev[rk]    = v;
        rank2d[i_ * NPTS + j_] = (short)rk;
        rank2d[j_ * NPTS + i_] = (short)rk;
    }
    __syncthreads();          // ranking done; sDm dead, M takes over (no init needed)

    if (wid != 0) return;     // ---- single-wave main loop ----

    int    rootv = lane;                              // DSU root of vertex==lane
    uint4  occ      = make_uint4(0u, 0u, 0u, 0u);     // live + dead-pending slots
    uint4  pendmask = make_uint4(0u, 0u, 0u, 0u);
    int    plc = 0, inuse = 0, bail = 0, merges = 0;
    double birth = 0.0, death = 0.0;

#define DO_FLUSH(upto)                                                          \
    {                                                                           \
        for (int x = lane; x < (upto); x += 64) {                               \
            uint4 row = uA.M[x];                                                \
            if (any4(row, pendmask)) uA.M[x] = pend_apply(row, pendmask, s_pend); \
        }                                                                       \
        uint4 mvr = Mv[lane];                                                   \
        if (any4(mvr, pendmask)) Mv[lane] = pend_apply(mvr, pendmask, s_pend);  \
        occ.x &= ~pendmask.x; occ.y &= ~pendmask.y;                             \
        occ.z &= ~pendmask.z; occ.w &= ~pendmask.w;                             \
        inuse -= plc; plc = 0;                                                  \
        pendmask = make_uint4(0u, 0u, 0u, 0u);                                  \
    }

    int r = 0;
    while (r < NEDGE) {
        if (merges < NPTS - 1) {
            // ================= singles (validated R7 body) =================
            if (inuse >= 126) {
                DO_FLUSH(r);
                if (inuse >= 126) { bail = 1; break; }
            }
            const unsigned short ij = se_ij[r];
            const int i_ = ij & 255, j_ = ij >> 8;
            const float evr = ev[r];
            const int rootI = __shfl(rootv, i_);
            const int rootJ = __shfl(rootv, j_);
            uint4 ann = Mv[i_];
            { uint4 t = Mv[j_]; xor4(ann, t); }
            if (rootI != rootJ) {
                rootv = (rootv == rootI) ? rootJ : rootv;
                ++merges;
            } else {
                birth += (double)evr;
                uint4 free4 = make_uint4(~occ.x, ~occ.y, ~occ.z, ~occ.w);
                int s = ffs4set(free4);
                if (s < 0) { bail = 1; break; }
                set4(occ, s); ++inuse;
                set4(ann, s);
            }
            if (lane == 0) uA.M[r] = ann;
            const short a_l = rank2d[i_ * NPTS + lane];
            const short b_l = rank2d[j_ * NPTS + lane];
            const bool validk = (lane != i_) && (lane != j_) && (a_l < r) && (b_l < r);
            if (__ballot(validk)) {
                uint4 v = make_uint4(0u, 0u, 0u, 0u);
                if (validk) {
                    v = uA.M[a_l];
                    { uint4 t = uA.M[b_l]; xor4(v, t); }
                    xor4(v, ann);
                    v = pend_apply(v, pendmask, s_pend);
                }
                gj_append(v, evr, lane, s_pend, s_plist, plc, pendmask, death);
            }
            ++r;
        } else {
            // ================= batched steady state (all edges positive) =================
            if (inuse >= 120) {
                DO_FLUSH(r);
                if (inuse >= 120) { bail = 1; break; }
            }
            const int lim = (NEDGE - r < 4) ? (NEDGE - r) : 4;
            int i0 = 0, j0 = 0, i1 = 0, j1 = 0, i2 = 0, j2 = 0, i3 = 0, j3 = 0;
            float e0 = 0.f, e1 = 0.f, e2 = 0.f, e3 = 0.f;
            unsigned long long m0 = 0, m1 = 0, m2 = 0, m3 = 0;
            int c0 = 0, c1 = 0, c2 = 0, c3 = 0;
            {
                const unsigned short ij = se_ij[r];
                i0 = ij & 255; j0 = ij >> 8; e0 = ev[r];
                const short a = rank2d[i0 * NPTS + lane], b = rank2d[j0 * NPTS + lane];
                m0 = __ballot((lane != i0) && (lane != j0) && (a < r) && (b < r));
                c0 = (int)__popcll(m0);
            }
            if (lim > 1) {
                const unsigned short ij = se_ij[r + 1];
                i1 = ij & 255; j1 = ij >> 8; e1 = ev[r + 1];
                const short a = rank2d[i1 * NPTS + lane], b = rank2d[j1 * NPTS + lane];
                m1 = __ballot((lane != i1) && (lane != j1) && (a < r + 1) && (b < r + 1));
                c1 = (int)__popcll(m1);
            }
            if (lim > 2) {
                const unsigned short ij = se_ij[r + 2];
                i2 = ij & 255; j2 = ij >> 8; e2 = ev[r + 2];
                const short a = rank2d[i2 * NPTS + lane], b = rank2d[j2 * NPTS + lane];
                m2 = __ballot((lane != i2) && (lane != j2) && (a < r + 2) && (b < r + 2));
                c2 = (int)__popcll(m2);
            }
            if (lim > 3) {
                const unsigned short ij = se_ij[r + 3];
                i3 = ij & 255; j3 = ij >> 8; e3 = ev[r + 3];
                const short a = rank2d[i3 * NPTS + lane], b = rank2d[j3 * NPTS + lane];
                m3 = __ballot((lane != i3) && (lane != j3) && (a < r + 3) && (b < r + 3));
                c3 = (int)__popcll(m3);
            }
            int B = 1, tot = c0;
            if (lim > 1 && tot + c1 <= 64) {
                B = 2; tot += c1;
                if (lim > 2 && tot + c2 <= 64) {
                    B = 3; tot += c2;
                    if (lim > 3 && tot + c3 <= 64) { B = 4; tot += c3; }
                }
            }
            // slots (inuse < 120 => plenty free)
            uint4 free4 = make_uint4(~occ.x, ~occ.y, ~occ.z, ~occ.w);
            const int s0 = ffs4set(free4);
            const int s1 = (B > 1) ? ffs4set(free4) : 0;
            const int s2 = (B > 2) ? ffs4set(free4) : 0;
            const int s3 = (B > 3) ? ffs4set(free4) : 0;
            // events: all positive
            birth += (double)e0 + (B > 1 ? (double)e1 : 0.0)
                   + (B > 2 ? (double)e2 : 0.0) + (B > 3 ? (double)e3 : 0.0);
            set4(occ, s0);
            if (B > 1) set4(occ, s1);
            if (B > 2) set4(occ, s2);
            if (B > 3) set4(occ, s3);
            inuse += B;
            if (lane < B) {
                const int ii = SEL4(lane, i0, i1, i2, i3);
                const int jj = SEL4(lane, j0, j1, j2, j3);
                const int ss = SEL4(lane, s0, s1, s2, s3);
                uint4 annw = Mv[ii];
                { uint4 t = Mv[jj]; xor4(annw, t); }
                set4(annw, ss);
                uA.M[r + lane] = annw;
            }
            if (tot) {
                const int P1 = c0, P2 = P1 + c1, P3 = P2 + c2;
                const bool act = lane < tot;
                const int gsel = (lane < P1) ? 0 : (lane < P2) ? 1 : (lane < P3) ? 2 : 3;
                const int off  = lane - ((gsel == 0) ? 0 : (gsel == 1) ? P1 : (gsel == 2) ? P2 : P3);
                const unsigned long long msel = SEL4(gsel, m0, m1, m2, m3);
                const int k  = act ? nth_set_bit64(msel, off) : 0;
                const int ii = SEL4(gsel, i0, i1, i2, i3);
                const int jj = SEL4(gsel, j0, j1, j2, j3);
                const int ss = SEL4(gsel, s0, s1, s2, s3);
                const float evl = SEL4(gsel, e0, e1, e2, e3);
                uint4 v = make_uint4(0u, 0u, 0u, 0u);
                if (act) {
                    const short a = rank2d[ii * NPTS + k];
                    const short b = rank2d[jj * NPTS + k];
                    uint4 ann2 = Mv[ii];
                    { uint4 t = Mv[jj]; xor4(ann2, t); }
                    set4(ann2, ss);
                    v = uA.M[a];
                    { uint4 t = uA.M[b]; xor4(v, t); }
                    xor4(v, ann2);
                    v = pend_apply(v, pendmask, s_pend);
                }
                gj_append(v, evl, lane, s_pend, s_plist, plc, pendmask, death);
            }
            r += B;
        }
    }
#undef DO_FLUSH

    if (lane == 0) {
        if (bail) g_ovf[cls] = 1;
        else      g_tp[cls] = (float)(death - birth);
    }
}

// ---------------- fallback: R3's validated exact Row-matrix reduction ----------------
__global__ __launch_bounds__(1024) void persist_exact_k() {
    const int cls  = blockIdx.x;
    const int tid  = threadIdx.x;
    const int lane = tid & 63;
    const int wid  = tid >> 6;
    if (g_counts[cls] < MIN_SAMP) return;
    if (!g_ovf[cls]) return;

    union PhaseU {
        float        sDm[NPTS * NPTS];
        unsigned int pbuf[62][64];
    };
    __shared__ PhaseU        u;
    __shared__ short         rank2d[NPTS * NPTS];
    __shared__ unsigned char e2i[NEDGE], e2j[NEDGE];
    __shared__ unsigned char se_i[NEDGE], se_j[NEDGE];
    __shared__ float         ev[NEDGE];
    __shared__ unsigned char cstate[64];
    __shared__ int           s_t;
    __shared__ double        s_birth, s_death;
    __shared__ unsigned char parent[NPTS];

    for (int p = tid; p < NPTS * NPTS; p += 1024) u.sDm[p] = g_Dm[cls][p];
    if (tid < NPTS - 1) {
        int i = tid;
        int base = i * (2 * NPTS - 1 - i) / 2;
        for (int j = i + 1; j < NPTS; ++j) {
            e2i[base + j - i - 1] = (unsigned char)i;
            e2j[base + j - i - 1] = (unsigned char)j;
        }
    }
    for (int x = tid; x < NEDGE * 64; x += 1024) {
        int rr = x >> 6, w = x & 63;
        g_rows[cls][rr][w] = (w == (rr >> 5)) ? (1u << (rr & 31)) : 0u;
    }
    if (tid < NPTS) rank2d[tid * NPTS + tid] = 0x7fff;
    __syncthreads();

    for (int e = tid; e < NEDGE; e += 1024) {
        int i_ = e2i[e], j_ = e2j[e];
        float v = u.sDm[i_ * NPTS + j_];
        int rk = 0;
        for (int f = 0; f < NEDGE; ++f) {
            int fi = e2i[f], fj = e2j[f];
            float w = u.sDm[fi * NPTS + fj];
            bool less = (w < v) || (w == v && (fi < i_ || (fi == i_ && fj < j_)));
            rk += less ? 1 : 0;
        }
        se_i[rk] = (unsigned char)i_;
        se_j[rk] = (unsigned char)j_;
        ev[rk]   = v;
        rank2d[i_ * NPTS + j_] = (short)rk;
        rank2d[j_ * NPTS + i_] = (short)rk;
    }
    __syncthreads();

    if (tid == 0) {
        for (int i = 0; i < NPTS; ++i) parent[i] = (unsigned char)i;
        double bs = 0.0;
        for (int r = 0; r < NEDGE; ++r) {
            int x = se_i[r]; while (parent[x] != x) { parent[x] = parent[parent[x]]; x = parent[x]; }
            int y = se_j[r]; while (parent[y] != y) { parent[y] = parent[parent[y]]; y = parent[y]; }
            if (x == y) bs += (double)ev[r];
            else parent[x] = (unsigned char)y;
        }
        s_birth = bs; s_death = 0.0;
    }
    __syncthreads();

    unsigned int (*Row)[64] = g_rows[cls];

    for (int r = 1; r < NEDGE; ++r) {
        const int i_ = se_i[r], j_ = se_j[r];
        const int a_l = rank2d[i_ * NPTS + lane];
        const int b_l = rank2d[j_ * NPTS + lane];
        const bool valid = (lane != i_) && (lane != j_) && (a_l < r) && (b_l < r);
        const unsigned long long mask = __ballot(valid);
        if (!mask) continue;
        const int cnt = __popcll(mask);

        {
            const unsigned int rrow = Row[r][lane];
            for (int idx = wid; idx < cnt; idx += 16) {
                unsigned long long mm = mask;
                for (int s = 0; s < idx; ++s) mm &= mm - 1;
                const int k = __builtin_ctzll(mm);
                const int a = __shfl(a_l, k);
                const int b = __shfl(b_l, k);
                const unsigned int p = Row[a][lane] ^ Row[b][lane] ^ rrow;
                u.pbuf[idx][lane] = p;
                const bool indep = (__ballot(p != 0u) != 0ull);
                if (lane == 0) cstate[idx] = indep ? 1 : 0;
            }
        }
        __syncthreads();

        while (true) {
            int c = -1;
            for (int x = 0; x < cnt; ++x) if (cstate[x] == 1) { c = x; break; }
            if (c < 0) break;
            __syncthreads();
            if (wid == 0) {
                const unsigned int pw = u.pbuf[c][lane];
                const unsigned long long m2 = __ballot(pw != 0u);
                const int fl = __builtin_ctzll(m2);
                const unsigned int w0 = (unsigned int)__shfl((int)pw, fl);
                if (lane == 0) s_t = fl * 32 + __builtin_ctz(w0);
            }
            if (tid == 0) { s_death += (double)ev[r]; cstate[c] = 2; }
            __syncthreads();
            const int t = s_t, tw = t >> 5;
            const unsigned int tb = 1u << (t & 31);
            const unsigned int pw = u.pbuf[c][lane];
            for (int rr0 = wid * 64; rr0 < NEDGE; rr0 += 1024) {
                const int rr = rr0 + lane;
                unsigned int hit = (rr < NEDGE) ? (Row[rr][tw] & tb) : 0u;
                unsigned long long mrows = __ballot(hit != 0u);
                while (mrows) {
                    const int rx = rr0 + __builtin_ctzll(mrows);
                    mrows &= mrows - 1;
                    Row[rx][lane] ^= pw;
                }
            }
            __threadfence_block();
            __syncthreads();
            {
                const unsigned int rrow2 = Row[r][lane];
                for (int idx = wid; idx < cnt; idx += 16) {
                    if (cstate[idx] != 1) continue;
                    unsigned long long mm = mask;
                    for (int s = 0; s < idx; ++s) mm &= mm - 1;
                    const int k = __builtin_ctzll(mm);
                    const int a = __shfl(a_l, k);
                    const int b = __shfl(b_l, k);
                    const unsigned int p2 = Row[a][lane] ^ Row[b][lane] ^ rrow2;
                    u.pbuf[idx][lane] = p2;
                    const bool indep = (__ballot(p2 != 0u) != 0ull);
                    if (lane == 0) cstate[idx] = indep ? 1 : 0;
                }
            }
            __syncthreads();
        }
        __syncthreads();
    }

    if (tid == 0) g_tp[cls] = (float)(s_death - s_birth);
}

__global__ void final_k(const float* __restrict__ tgt, float* __restrict__ out) {
    double total = 0.0;
    int valid = 0;
    for (int c = 0; c < NCLS; ++c) {
        if (g_counts[c] >= MIN_SAMP) {
            double tpt = 0.0;
            for (int p = 0; p < 100; ++p)
                tpt += (double)tgt[(c * 100 + p) * 2 + 1] - (double)tgt[(c * 100 + p) * 2 + 0];
            double d = (double)g_tp[c] - tpt;
            total += d * d;
            valid++;
        }
    }
    *out = valid ? (float)(total / valid) : 0.0f;
}

extern "C" void kernel_launch(void* const* d_in, const int* in_sizes, int n_in,
                              void* d_out, int out_size, void* d_ws, size_t ws_size,
                              hipStream_t stream) {
    const float* feat   = (const float*)d_in[0];
    const int*   labels = (const int*)d_in[1];
    const float* tgt    = (const float*)d_in[2];
    const int N = in_sizes[1];

    hipLaunchKernelGGL(init_k,         dim3(1),        dim3(64),   0, stream);
    hipLaunchKernelGGL(count_k,        dim3(256),      dim3(256),  0, stream, labels, N);
    hipLaunchKernelGGL(select_k,       dim3(1),        dim3(64),   0, stream, labels, N);
    hipLaunchKernelGGL(dist_k,         dim3(NCLS, 16), dim3(256),  0, stream, feat);
    hipLaunchKernelGGL(persist_fast_k, dim3(NCLS),     dim3(1024), 0, stream);
    hipLaunchKernelGGL(persist_exact_k,dim3(NCLS),     dim3(1024), 0, stream);
    hipLaunchKernelGGL(final_k,        dim3(1),        dim3(1),    0, stream, tgt, (float*)d_out);
}

// Round 12
// 2802.463 us; speedup vs baseline: 1.2322x; 1.2322x over previous
//
#include <hip/hip_runtime.h>
#include <hip/hip_bf16.h>

#define NCLS 3
#define NPTS 64
#define NEDGE 2016   // 64*63/2
#define MIN_SAMP 200
#define PENDCAP 128

__device__ int          g_counts[NCLS];
__device__ int          g_sel[NCLS][NPTS];
__device__ float        g_Dm[NCLS][NPTS * NPTS];
__device__ float        g_tp[NCLS];
__device__ int          g_ovf[NCLS];
__device__ unsigned int g_rows[NCLS][NEDGE][64];   // fallback-only state

__global__ void init_k() {
    if (threadIdx.x < NCLS) { g_counts[threadIdx.x] = 0; g_ovf[threadIdx.x] = 0; }
}

__global__ __launch_bounds__(256) void count_k(const int* __restrict__ labels, int N) {
    __shared__ int c3[NCLS];
    if (threadIdx.x < NCLS) c3[threadIdx.x] = 0;
    __syncthreads();
    for (int i = blockIdx.x * blockDim.x + threadIdx.x; i < N; i += gridDim.x * blockDim.x) {
        int c = labels[i];
        if ((unsigned)c < NCLS) atomicAdd(&c3[c], 1);
    }
    __syncthreads();
    if (threadIdx.x < NCLS) atomicAdd(&g_counts[threadIdx.x], c3[threadIdx.x]);
}

__global__ __launch_bounds__(64) void select_k(const int* __restrict__ labels, int N) {
    const int lane = threadIdx.x;
    int cnt[NCLS] = {0, 0, 0};
    for (int base = 0; base < N; base += 64) {
        if (cnt[0] >= NPTS && cnt[1] >= NPTS && cnt[2] >= NPTS) break;
        int lab = (base + lane < N) ? labels[base + lane] : -1;
        for (int c = 0; c < NCLS; ++c) {
            if (cnt[c] >= NPTS) continue;
            unsigned long long m = __ballot(lab == c);
            if (!m) continue;
            int pos = cnt[c] + __popcll(m & ((1ull << lane) - 1ull));
            if (lab == c && pos < NPTS) g_sel[c][pos] = base + lane;
            cnt[c] = min(NPTS, cnt[c] + (int)__popcll(m));
        }
    }
}

__global__ __launch_bounds__(256) void dist_k(const float* __restrict__ feat) {
    int cls = blockIdx.x;
    if (g_counts[cls] < MIN_SAMP) return;
    int p = blockIdx.y * 256 + threadIdx.x;
    int i = p >> 6, j = p & 63;
    const float4* pi = (const float4*)(feat + (size_t)g_sel[cls][i] * 768);
    const float4* pj = (const float4*)(feat + (size_t)g_sel[cls][j] * 768);
    float sq = 0.f;
    #pragma unroll 4
    for (int d = 0; d < 192; ++d) {
        float4 va = pi[d], vb = pj[d];
        float dx = va.x - vb.x, dy = va.y - vb.y, dz = va.z - vb.z, dw = va.w - vb.w;
        sq = fmaf(dx, dx, sq); sq = fmaf(dy, dy, sq);
        sq = fmaf(dz, dz, sq); sq = fmaf(dw, dw, sq);
    }
    g_Dm[cls][p] = sqrtf(fmaxf(sq, 1e-12f));
}

__device__ __forceinline__ uint4 shfl4(uint4 v, int src) {
    uint4 r;
    r.x = (unsigned)__shfl((int)v.x, src);
    r.y = (unsigned)__shfl((int)v.y, src);
    r.z = (unsigned)__shfl((int)v.z, src);
    r.w = (unsigned)__shfl((int)v.w, src);
    return r;
}
__device__ __forceinline__ void xor4(uint4& a, const uint4 b) {
    a.x ^= b.x; a.y ^= b.y; a.z ^= b.z; a.w ^= b.w;
}
__device__ __forceinline__ unsigned int getw4(const uint4 a, int m) {
    return (m < 32) ? a.x : (m < 64) ? a.y : (m < 96) ? a.z : a.w;
}
__device__ __forceinline__ void set4(uint4& a, int m) {
    const unsigned int b = 1u << (m & 31);
    if (m < 32) a.x |= b; else if (m < 64) a.y |= b; else if (m < 96) a.z |= b; else a.w |= b;
}

// apply mutually-reduced pending updates to v (order-free; see theory)
__device__ __forceinline__ uint4 pend_apply(uint4 v, const uint4 pm,
                                            const uint4* s_pend, const unsigned char* s_pidx) {
    unsigned int w;
    w = v.x & pm.x;
    while (w) { int c = __builtin_ctz(w); w &= w - 1; xor4(v, s_pend[s_pidx[c]]); }
    w = v.y & pm.y;
    while (w) { int c = __builtin_ctz(w); w &= w - 1; xor4(v, s_pend[s_pidx[32 + c]]); }
    w = v.z & pm.z;
    while (w) { int c = __builtin_ctz(w); w &= w - 1; xor4(v, s_pend[s_pidx[64 + c]]); }
    w = v.w & pm.w;
    while (w) { int c = __builtin_ctz(w); w &= w - 1; xor4(v, s_pend[s_pidx[96 + c]]); }
    return v;
}

// ---------------- fast path: annotation H1 persistence, lazy batched updates ----------------
__global__ __launch_bounds__(1024) void persist_fast_k() {
    const int cls  = blockIdx.x;
    const int tid  = threadIdx.x;
    const int lane = tid & 63;
    const int wid  = tid >> 6;
    if (g_counts[cls] < MIN_SAMP) return;

    __shared__ union UA {
        float sDm[NPTS * NPTS];          // ranking phase (16 KB)
        uint4 M[NEDGE];                  // edge annotations (32.25 KB)
    } uA;
    __shared__ short         rank2d[NPTS * NPTS];       // 8 KB
    __shared__ unsigned char se_i[NEDGE], se_j[NEDGE];  // 4 KB
    __shared__ float         ev[NEDGE];                 // 8 KB
    __shared__ unsigned char e2i[NEDGE], e2j[NEDGE];    // 4 KB (ranking only)
    __shared__ uint4         s_pend[PENDCAP];           // 2 KB
    __shared__ unsigned char s_pidx[128];

    for (int p = tid; p < NPTS * NPTS; p += 1024) uA.sDm[p] = g_Dm[cls][p];
    if (tid < NPTS - 1) {
        int i = tid;
        int base = i * (2 * NPTS - 1 - i) / 2;
        for (int j = i + 1; j < NPTS; ++j) {
            e2i[base + j - i - 1] = (unsigned char)i;
            e2j[base + j - i - 1] = (unsigned char)j;
        }
    }
    if (tid < NPTS) rank2d[tid * NPTS + tid] = 0x7fff;   // diagonal guard
    __syncthreads();

    // Rank edges by (value, i, j) — matches reference lexsort((jj,ii,vals)).
    for (int e = tid; e < NEDGE; e += 1024) {
        int i_ = e2i[e], j_ = e2j[e];
        float v = uA.sDm[i_ * NPTS + j_];
        int rk = 0;
        for (int f = 0; f < NEDGE; ++f) {
            int fi = e2i[f], fj = e2j[f];
            float w = uA.sDm[fi * NPTS + fj];
            bool less = (w < v) || (w == v && (fi < i_ || (fi == i_ && fj < j_)));
            rk += less ? 1 : 0;
        }
        se_i[rk] = (unsigned char)i_;
        se_j[rk] = (unsigned char)j_;
        ev[rk]   = v;
        rank2d[i_ * NPTS + j_] = (short)rk;
        rank2d[j_ * NPTS + i_] = (short)rk;
    }
    __syncthreads();          // ranking done; sDm dead, M takes over (no init needed)

    if (wid != 0) return;     // ---- single-wave main loop ----

    // Per-lane registers: DSU root and annotation potential of vertex==lane.
    int   rootv = lane;
    uint4 pi    = make_uint4(0u, 0u, 0u, 0u);
    // Uniform state (all lanes compute identically):
    uint4 occ      = make_uint4(0u, 0u, 0u, 0u);
    uint4 pendmask = make_uint4(0u, 0u, 0u, 0u);
    int   pcount = 0, inuse = 0, bail = 0;
    double birth = 0.0, death = 0.0;

    for (int r = 0; r < NEDGE; ++r) {
        // ---- flush pending when list or slot pressure is high ----
        if (pcount >= 64 || inuse >= 126) {
            for (int x = lane; x < r; x += 64) {
                uint4 row = uA.M[x];
                const unsigned int anyw = (row.x & pendmask.x) | (row.y & pendmask.y)
                                        | (row.z & pendmask.z) | (row.w & pendmask.w);
                if (anyw) uA.M[x] = pend_apply(row, pendmask, s_pend, s_pidx);
            }
            pi = pend_apply(pi, pendmask, s_pend, s_pidx);
            occ.x &= ~pendmask.x; occ.y &= ~pendmask.y;
            occ.z &= ~pendmask.z; occ.w &= ~pendmask.w;
            inuse -= pcount; pcount = 0;
            pendmask = make_uint4(0u, 0u, 0u, 0u);
            if (inuse >= 127) { bail = 1; break; }   // genuine beta_1 overflow
        }

        const int i_ = se_i[r], j_ = se_j[r];
        const float evr = ev[r];

        // ---- edge event, fully uniform & registerized ----
        const int rootI = __shfl(rootv, i_);
        const int rootJ = __shfl(rootv, j_);
        uint4 ann = shfl4(pi, i_);
        xor4(ann, shfl4(pi, j_));
        if (rootI != rootJ) {
            rootv = (rootv == rootI) ? rootJ : rootv;    // merge (full compression kept)
        } else {
            birth += (double)evr;                        // positive edge: new class
            int s = (~occ.x) ? __builtin_ctz(~occ.x)
                  : (~occ.y) ? 32 + __builtin_ctz(~occ.y)
                  : (~occ.z) ? 64 + __builtin_ctz(~occ.z)
                  : (~occ.w) ? 96 + __builtin_ctz(~occ.w) : -1;
            if (s < 0) { bail = 1; break; }
            set4(occ, s); ++inuse;
            set4(ann, s);
        }
        if (lane == 0) uA.M[r] = ann;                    // stored stale-basis; ann reused below

        // ---- candidate triangles of this group ----
        const int a_l = rank2d[i_ * NPTS + lane];
        const int b_l = rank2d[j_ * NPTS + lane];
        const bool validk = (lane != i_) && (lane != j_) && (a_l < r) && (b_l < r);
        if (!__ballot(validk)) continue;

        uint4 v = make_uint4(0u, 0u, 0u, 0u);
        if (validk) {
            v = uA.M[a_l];
            xor4(v, uA.M[b_l]);
            xor4(v, ann);
            v = pend_apply(v, pendmask, s_pend, s_pidx); // bring to current basis
        }

        // ---- wave-synchronous Gauss-Jordan over valid lanes ----
        uint4 s4 = make_uint4(0u, 0u, 0u, 0u);
        int accidx = -1, accm = 0;
        int d = 0;
        while (true) {
            unsigned long long nzm = __ballot((v.x | v.y | v.z | v.w) != 0u);
            if (!nzm) break;
            const int l = __builtin_ctzll(nzm);
            const uint4 p = shfl4(v, l);
            const int m = p.x ? __builtin_ctz(p.x) : p.y ? 32 + __builtin_ctz(p.y)
                       : p.z ? 64 + __builtin_ctz(p.z) : 96 + __builtin_ctz(p.w);
            if (lane == l) { s4 = v; accidx = d; accm = m; }
            const unsigned int mb2 = 1u << (m & 31);
            if (getw4(v, m) & mb2) xor4(v, p);
            if (accidx >= 0 && accidx < d) {
                if (getw4(s4, m) & mb2) xor4(s4, p);
            }
            ++d;
        }
        if (d == 0) continue;
        death += (double)d * (double)evr;

        // ---- append new pending updates (mutually-reduced form) ----
        const int pbase = pcount;
        if (accidx >= 0) {
            s_pend[pbase + accidx] = s4;
            s_pidx[accm] = (unsigned char)(pbase + accidx);
        }
        for (int t = 0; t < d; ++t) {
            const unsigned long long who = __ballot(accidx == t);
            const int l = __builtin_ctzll(who);
            const int m = __shfl(accm, l);
            const uint4 u4 = shfl4(s4, l);
            set4(pendmask, m);
            const unsigned int mb2 = 1u << (m & 31);
            for (int x = lane; x < pbase; x += 64) {     // keep old pending reduced vs new pivot
                uint4 q = s_pend[x];
                if (getw4(q, m) & mb2) { xor4(q, u4); s_pend[x] = q; }
            }
        }
        pcount += d;
    }

    if (lane == 0) {
        if (bail) g_ovf[cls] = 1;
        else      g_tp[cls] = (float)(death - birth);
    }
}

// ---------------- fallback: R3's validated exact Row-matrix reduction ----------------
__global__ __launch_bounds__(1024) void persist_exact_k() {
    const int cls  = blockIdx.x;
    const int tid  = threadIdx.x;
    const int lane = tid & 63;
    const int wid  = tid >> 6;
    if (g_counts[cls] < MIN_SAMP) return;
    if (!g_ovf[cls]) return;

    union PhaseU {
        float        sDm[NPTS * NPTS];
        unsigned int pbuf[62][64];
    };
    __shared__ PhaseU        u;
    __shared__ short         rank2d[NPTS * NPTS];
    __shared__ unsigned char e2i[NEDGE], e2j[NEDGE];
    __shared__ unsigned char se_i[NEDGE], se_j[NEDGE];
    __shared__ float         ev[NEDGE];
    __shared__ unsigned char cstate[64];
    __shared__ int           s_t;
    __shared__ double        s_birth, s_death;
    __shared__ unsigned char parent[NPTS];

    for (int p = tid; p < NPTS * NPTS; p += 1024) u.sDm[p] = g_Dm[cls][p];
    if (tid < NPTS - 1) {
        int i = tid;
        int base = i * (2 * NPTS - 1 - i) / 2;
        for (int j = i + 1; j < NPTS; ++j) {
            e2i[base + j - i - 1] = (unsigned char)i;
            e2j[base + j - i - 1] = (unsigned char)j;
        }
    }
    for (int x = tid; x < NEDGE * 64; x += 1024) {
        int rr = x >> 6, w = x & 63;
        g_rows[cls][rr][w] = (w == (rr >> 5)) ? (1u << (rr & 31)) : 0u;
    }
    if (tid < NPTS) rank2d[tid * NPTS + tid] = 0x7fff;
    __syncthreads();

    for (int e = tid; e < NEDGE; e += 1024) {
        int i_ = e2i[e], j_ = e2j[e];
        float v = u.sDm[i_ * NPTS + j_];
        int rk = 0;
        for (int f = 0; f < NEDGE; ++f) {
            int fi = e2i[f], fj = e2j[f];
            float w = u.sDm[fi * NPTS + fj];
            bool less = (w < v) || (w == v && (fi < i_ || (fi == i_ && fj < j_)));
            rk += less ? 1 : 0;
        }
        se_i[rk] = (unsigned char)i_;
        se_j[rk] = (unsigned char)j_;
        ev[rk]   = v;
        rank2d[i_ * NPTS + j_] = (short)rk;
        rank2d[j_ * NPTS + i_] = (short)rk;
    }
    __syncthreads();

    if (tid == 0) {
        for (int i = 0; i < NPTS; ++i) parent[i] = (unsigned char)i;
        double bs = 0.0;
        for (int r = 0; r < NEDGE; ++r) {
            int x = se_i[r]; while (parent[x] != x) { parent[x] = parent[parent[x]]; x = parent[x]; }
            int y = se_j[r]; while (parent[y] != y) { parent[y] = parent[parent[y]]; y = parent[y]; }
            if (x == y) bs += (double)ev[r];
            else parent[x] = (unsigned char)y;
        }
        s_birth = bs; s_death = 0.0;
    }
    __syncthreads();

    unsigned int (*Row)[64] = g_rows[cls];

    for (int r = 1; r < NEDGE; ++r) {
        const int i_ = se_i[r], j_ = se_j[r];
        const int a_l = rank2d[i_ * NPTS + lane];
        const int b_l = rank2d[j_ * NPTS + lane];
        const bool valid = (lane != i_) && (lane != j_) && (a_l < r) && (b_l < r);
        const unsigned long long mask = __ballot(valid);
        if (!mask) continue;
        const int cnt = __popcll(mask);

        {
            const unsigned int rrow = Row[r][lane];
            for (int idx = wid; idx < cnt; idx += 16) {
                unsigned long long mm = mask;
                for (int s = 0; s < idx; ++s) mm &= mm - 1;
                const int k = __builtin_ctzll(mm);
                const int a = __shfl(a_l, k);
                const int b = __shfl(b_l, k);
                const unsigned int p = Row[a][lane] ^ Row[b][lane] ^ rrow;
                u.pbuf[idx][lane] = p;
                const bool indep = (__ballot(p != 0u) != 0ull);
                if (lane == 0) cstate[idx] = indep ? 1 : 0;
            }
        }
        __syncthreads();

        while (true) {
            int c = -1;
            for (int x = 0; x < cnt; ++x) if (cstate[x] == 1) { c = x; break; }
            if (c < 0) break;
            __syncthreads();
            if (wid == 0) {
                const unsigned int pw = u.pbuf[c][lane];
                const unsigned long long m2 = __ballot(pw != 0u);
                const int fl = __builtin_ctzll(m2);
                const unsigned int w0 = (unsigned int)__shfl((int)pw, fl);
                if (lane == 0) s_t = fl * 32 + __builtin_ctz(w0);
            }
            if (tid == 0) { s_death += (double)ev[r]; cstate[c] = 2; }
            __syncthreads();
            const int t = s_t, tw = t >> 5;
            const unsigned int tb = 1u << (t & 31);
            const unsigned int pw = u.pbuf[c][lane];
            for (int rr0 = wid * 64; rr0 < NEDGE; rr0 += 1024) {
                const int rr = rr0 + lane;
                unsigned int hit = (rr < NEDGE) ? (Row[rr][tw] & tb) : 0u;
                unsigned long long mrows = __ballot(hit != 0u);
                while (mrows) {
                    const int rx = rr0 + __builtin_ctzll(mrows);
                    mrows &= mrows - 1;
                    Row[rx][lane] ^= pw;
                }
            }
            __threadfence_block();
            __syncthreads();
            {
                const unsigned int rrow2 = Row[r][lane];
                for (int idx = wid; idx < cnt; idx += 16) {
                    if (cstate[idx] != 1) continue;
                    unsigned long long mm = mask;
                    for (int s = 0; s < idx; ++s) mm &= mm - 1;
                    const int k = __builtin_ctzll(mm);
                    const int a = __shfl(a_l, k);
                    const int b = __shfl(b_l, k);
                    const unsigned int p2 = Row[a][lane] ^ Row[b][lane] ^ rrow2;
                    u.pbuf[idx][lane] = p2;
                    const bool indep = (__ballot(p2 != 0u) != 0ull);
                    if (lane == 0) cstate[idx] = indep ? 1 : 0;
                }
            }
            __syncthreads();
        }
        __syncthreads();
    }

    if (tid == 0) g_tp[cls] = (float)(s_death - s_birth);
}

__global__ void final_k(const float* __restrict__ tgt, float* __restrict__ out) {
    double total = 0.0;
    int valid = 0;
    for (int c = 0; c < NCLS; ++c) {
        if (g_counts[c] >= MIN_SAMP) {
            double tpt = 0.0;
            for (int p = 0; p < 100; ++p)
                tpt += (double)tgt[(c * 100 + p) * 2 + 1] - (double)tgt[(c * 100 + p) * 2 + 0];
            double d = (double)g_tp[c] - tpt;
            total += d * d;
            valid++;
        }
    }
    *out = valid ? (float)(total / valid) : 0.0f;
}

extern "C" void kernel_launch(void* const* d_in, const int* in_sizes, int n_in,
                              void* d_out, int out_size, void* d_ws, size_t ws_size,
                              hipStream_t stream) {
    const float* feat   = (const float*)d_in[0];
    const int*   labels = (const int*)d_in[1];
    const float* tgt    = (const float*)d_in[2];
    const int N = in_sizes[1];

    hipLaunchKernelGGL(init_k,         dim3(1),        dim3(64),   0, stream);
    hipLaunchKernelGGL(count_k,        dim3(256),      dim3(256),  0, stream, labels, N);
    hipLaunchKernelGGL(select_k,       dim3(1),        dim3(64),   0, stream, labels, N);
    hipLaunchKernelGGL(dist_k,         dim3(NCLS, 16), dim3(256),  0, stream, feat);
    hipLaunchKernelGGL(persist_fast_k, dim3(NCLS),     dim3(1024), 0, stream);
    hipLaunchKernelGGL(persist_exact_k,dim3(NCLS),     dim3(1024), 0, stream);
    hipLaunchKernelGGL(final_k,        dim3(1),        dim3(1),    0, stream, tgt, (float*)d_out);
}